// Round 3
// baseline (64.735 us; speedup 1.0000x reference)
//
#include <hip/hip_runtime.h>
#include <hip/hip_cooperative_groups.h>
#include <math.h>

namespace cg = cooperative_groups;

#define N 256
#define H 128
#define E 64
#define K 4
#define M (N + 1)
#define WAVES 16
#define BLOCK 1024

// ---------------------------------------------------------------------------
// helpers
// ---------------------------------------------------------------------------
__device__ __forceinline__ float sigm(float x) {
    return __fdividef(1.0f, 1.0f + __expf(-x));
}

__device__ __forceinline__ float wave_sum(float v) {
#pragma unroll
    for (int d = 1; d < 64; d <<= 1) v += __shfl_xor(v, d, 64);
    return v;
}

__device__ __forceinline__ float readlane_f(float v, int l) {
    return __uint_as_float(__builtin_amdgcn_readlane(__float_as_uint(v), l));
}

// Bit-exact replication of cal_dist's per-pair math (numpy fp32, no FMA
// contraction). Roles: r = row idx, c = col idx, r < c. Returns d[r][c], d[c][r].
__device__ __forceinline__ void pairdist(
    float a1x, float a1y, float a2x, float a2y,
    float g1x, float g1y, float g2x, float g2y,
    float baseR, float baseC, float& d_rc, float& d_cr)
{
    float t  = __fmul_rn(__fsub_rn(a1y, a2y), __fsub_rn(g1x, g2x));
    float dn = -t;  // (a1x-a1x)*(...) == 0 exactly
    float ca = __fsub_rn(__fmul_rn(a1x, a2y), __fmul_rn(a1y, a2x));
    float gt = __fsub_rn(__fmul_rn(g1x, g2y), __fmul_rn(g1x, g2x));  // ref bug kept
    float n1 = __fsub_rn(__fmul_rn(ca, __fsub_rn(g1x, g2x)),
                         __fmul_rn(__fsub_rn(a1x, a2x), gt));
    float n2 = __fsub_rn(__fmul_rn(ca, __fsub_rn(g1y, g2y)),
                         __fmul_rn(__fsub_rn(a1y, a2x), gt));        // ref bug kept
    float safe = (dn == 0.0f) ? 1.0f : dn;
    float p1 = __fdiv_rn(n1, safe);
    float p2 = __fdiv_rn(n2, safe);
    bool cond = (dn != 0.0f) &&
                (__fmul_rn(__fsub_rn(a1x, p1), __fsub_rn(p1, g1x)) > 0.0f);
    float dx1 = __fsub_rn(a1x, p1), dy1 = __fsub_rn(a1y, p2);
    float d1p = __fsqrt_rn(__fadd_rn(__fmul_rn(dx1, dx1), __fmul_rn(dy1, dy1)));
    float dx2 = __fsub_rn(a2x, p1), dy2 = __fsub_rn(a2y, p2);
    float d2p = __fsqrt_rn(__fadd_rn(__fmul_rn(dx2, dx2), __fmul_rn(dy2, dy2)));
    d_rc = cond ? d1p : baseR;
    d_cr = cond ? d2p : baseC;
}

// ---------------------------------------------------------------------------
// Fused kernel (cooperative): phase P precompute -> grid.sync -> phase B main
// 256 blocks x 1024 threads (16 waves), 1 block/CU.
// ---------------------------------------------------------------------------
__global__ __launch_bounds__(BLOCK, 1) void gat_fused(
    const float* __restrict__ ha, const float* __restrict__ hg,
    const float* __restrict__ goal, const float* __restrict__ action,
    const float* __restrict__ W_emb, const float* __restrict__ b_emb,
    const float* __restrict__ W_gate, const float* __restrict__ b_gate,
    const float* __restrict__ W_gat, const float* __restrict__ a_src,
    const float* __restrict__ a_dst, const float* __restrict__ gat_bias,
    float* __restrict__ A1, float* __restrict__ A2, float* __restrict__ G2,
    float* __restrict__ u3g, float* __restrict__ u4g, float* __restrict__ ccg,
    float* __restrict__ vsrc, float* __restrict__ vdst,
    float* __restrict__ out)
{
    const int b    = blockIdx.x;
    const int tid  = threadIdx.x;
    const int wid  = tid >> 6;
    const int lane = tid & 63;

    __shared__ float  sRed[8][3][H];   // 12 KB, phase-P scratch
    __shared__ float2 sAct[N];
    __shared__ float2 sGoal[N];
    __shared__ float  sBase[N];
    __shared__ float  sDij[M];
    __shared__ float  sDji[M];
    __shared__ float  sW[WAVES][K][H]; // 32 KB
    __shared__ float  sMx[WAVES];
    __shared__ float  sL[WAVES][K];
    __shared__ float  sWfin[K][H];
    __shared__ float  sPart[8][H];

    // ======================= phase P: precompute =======================
    // A1/A2/G2 row b: f = tid&127, 8 g-slices of 16
    {
        const int f  = tid & (H - 1);
        const int sl = tid >> 7;
        const int g0 = sl * 16;
        float s1 = 0.f, s2 = 0.f, s3 = 0.f;
#pragma unroll
        for (int g = 0; g < 16; ++g) {
            const int gg = g0 + g;
            float w1 = W_gate[gg * H + f];
            float w2 = W_gate[(H + gg) * H + f];
            float av = ha[b * H + gg];
            float gv = hg[b * H + gg];
            s1 += av * w1;
            s2 += av * w2;
            s3 += gv * w2;
        }
        sRed[sl][0][f] = s1;
        sRed[sl][1][f] = s2;
        sRed[sl][2][f] = s3;
    }
    __syncthreads();
    if (tid < H) {
        float r1 = 0.f, r2 = 0.f, r3 = 0.f;
#pragma unroll
        for (int sl = 0; sl < 8; ++sl) {
            r1 += sRed[sl][0][tid];
            r2 += sRed[sl][1][tid];
            r3 += sRed[sl][2][tid];
        }
        A1[b * H + tid] = r1;
        A2[b * H + tid] = r2;
        G2[b * H + tid] = r3;
    }
    if (b < 8) {
        // vsrc/vdst slice: 64 (k,f) pairs, coalesced W_gat row reads
        const int k = b >> 1;
        const float2 as = *(const float2*)&a_src[k * H + lane * 2];
        const float2 ad = *(const float2*)&a_dst[k * H + lane * 2];
#pragma unroll
        for (int it = 0; it < 4; ++it) {
            const int pair = b * 64 + wid * 4 + it;
            const int f    = pair & (H - 1);
            const float2 w = *(const float2*)&W_gat[(k * H + f) * H + lane * 2];
            float vs = wave_sum(w.x * as.x + w.y * as.y);
            float vv = wave_sum(w.x * ad.x + w.y * ad.y);
            if (lane == 0) { vsrc[k * H + f] = vs; vdst[k * H + f] = vv; }
        }
    } else if (b == 8) {
        __syncthreads();   // A-row readers done with sRed
        const int f  = tid & (H - 1);
        const int sl = tid >> 7;
        float s3 = 0.f, s4 = 0.f, scc = 0.f;
#pragma unroll
        for (int e0 = 0; e0 < 8; ++e0) {
            const int e = sl * 8 + e0;
            float w3 = W_gate[(2 * H + e) * H + f];
            float w4 = W_gate[(2 * H + E + e) * H + f];
            float we = W_emb[e], be = b_emb[e];
            s3  += we * w3;
            s4  += we * w4;
            scc += be * (w3 + w4);
        }
        sRed[sl][0][f] = s3;
        sRed[sl][1][f] = s4;
        sRed[sl][2][f] = scc;
        __syncthreads();
        if (tid < H) {
            float r3 = 0.f, r4 = 0.f, rc = 0.f;
#pragma unroll
            for (int sl = 0; sl < 8; ++sl) {
                r3 += sRed[sl][0][tid];
                r4 += sRed[sl][1][tid];
                rc += sRed[sl][2][tid];
            }
            u3g[tid] = r3;
            u4g[tid] = r4;
            ccg[tid] = rc + b_gate[tid];
        }
    }

    cg::this_grid().sync();

    // ======================= phase B: main =======================
    const int i    = b;
    const int f0   = lane * 2;
    const int kown = lane & 3;

    // geometry staging + bit-exact base recompute
    for (int t = tid; t < N; t += BLOCK) {
        float2 a = ((const float2*)action)[t];
        float2 g = ((const float2*)goal)[t];
        sAct[t]  = a;
        sGoal[t] = g;
        float dx = __fsub_rn(a.x, g.x), dy = __fsub_rn(a.y, g.y);
        sBase[t] = __fsqrt_rn(__fadd_rn(__fmul_rn(dx, dx), __fmul_rn(dy, dy)));
    }
    __syncthreads();

    // pass 0: all 257 distance pairs (bit-identical pairdist)
    if (tid < M) {
        const int j = tid;
        float dij = 0.f, dji = 0.f;
        if (j != i && j != N) {
            const float2 aI = sAct[i], gI = sGoal[i];
            const float2 aJ = sAct[j], gJ = sGoal[j];
            if (i < j)
                pairdist(aI.x, aI.y, aJ.x, aJ.y, gI.x, gI.y, gJ.x, gJ.y,
                         sBase[i], sBase[j], dij, dji);
            else
                pairdist(aJ.x, aJ.y, aI.x, aI.y, gJ.x, gJ.y, gI.x, gI.y,
                         sBase[j], sBase[i], dji, dij);
        }
        sDij[j] = dij;
        sDji[j] = dji;
    }

    // per-lane constants (2 features per lane)
    const float2 a1v = *(const float2*)&A1[i * H + f0];
    const float2 haI = *(const float2*)&ha[i * H + f0];
    const float2 hgI = *(const float2*)&hg[i * H + f0];
    const float2 g2v = *(const float2*)&G2[i * H + f0];
    const float2 u3  = *(const float2*)&u3g[f0];
    const float2 u4  = *(const float2*)&u4g[f0];
    const float2 cc  = *(const float2*)&ccg[f0];
    const float2 a1cc = make_float2(a1v.x + cc.x, a1v.y + cc.y);
    float2 vd[K];
#pragma unroll
    for (int k = 0; k < K; ++k) vd[k] = *(const float2*)&vdst[k * H + f0];

    // sc[k] = ha[i] . v_src[k]; keep own-k copy per lane
    float scOwn;
    {
        float sc0, sc1, sc2, sc3;
        { float2 vs = *(const float2*)&vsrc[0 * H + f0]; sc0 = wave_sum(haI.x * vs.x + haI.y * vs.y); }
        { float2 vs = *(const float2*)&vsrc[1 * H + f0]; sc1 = wave_sum(haI.x * vs.x + haI.y * vs.y); }
        { float2 vs = *(const float2*)&vsrc[2 * H + f0]; sc2 = wave_sum(haI.x * vs.x + haI.y * vs.y); }
        { float2 vs = *(const float2*)&vsrc[3 * H + f0]; sc3 = wave_sum(haI.x * vs.x + haI.y * vs.y); }
        scOwn = sc0;
        if (kown == 1) scOwn = sc1;
        else if (kown == 2) scOwn = sc2;
        else if (kown == 3) scOwn = sc3;
    }

    const float baseI = sBase[i];
    __syncthreads();   // sDij/sDji ready

    // online softmax state (shared wave max m_, own-k l_, per-f w accumulators)
    float m_ = -INFINITY, l_ = 0.f;
    float w0[K] = {0.f, 0.f, 0.f, 0.f};
    float w1[K] = {0.f, 0.f, 0.f, 0.f};

    // pair loop: wave handles j = wid + 16s, s = 0..15, as 8 pairs (j, j+16)
    int jA = wid, jB = wid + 16;
    float2 a2A = *(const float2*)&A2[jA * H + f0];
    float2 hA  = *(const float2*)&ha[jA * H + f0];
    float2 a2B = *(const float2*)&A2[jB * H + f0];
    float2 hB  = *(const float2*)&ha[jB * H + f0];

#pragma unroll 2
    for (int t = 0; t < 8; ++t) {
        float2 a2An = make_float2(0.f, 0.f), hAn = make_float2(0.f, 0.f);
        float2 a2Bn = make_float2(0.f, 0.f), hBn = make_float2(0.f, 0.f);
        if (t < 7) {
            a2An = *(const float2*)&A2[(jA + 32) * H + f0];
            hAn  = *(const float2*)&ha[(jA + 32) * H + f0];
            a2Bn = *(const float2*)&A2[(jB + 32) * H + f0];
            hBn  = *(const float2*)&ha[(jB + 32) * H + f0];
        }

        const float dijA = sDij[jA], djiA = sDji[jA];
        const float dijB = sDij[jB], djiB = sDji[jB];

        float txA = a1cc.x + a2A.x + dijA * u3.x + djiA * u4.x;
        float tyA = a1cc.y + a2A.y + dijA * u3.y + djiA * u4.y;
        float2 ginA = make_float2(hA.x * sigm(txA), hA.y * sigm(tyA));
        if (jA == i) ginA = haI;

        float txB = a1cc.x + a2B.x + dijB * u3.x + djiB * u4.x;
        float tyB = a1cc.y + a2B.y + dijB * u3.y + djiB * u4.y;
        float2 ginB = make_float2(hB.x * sigm(txB), hB.y * sigm(tyB));
        if (jB == i) ginB = haI;

        float qA0 = ginA.x * vd[0].x + ginA.y * vd[0].y;
        float qA1 = ginA.x * vd[1].x + ginA.y * vd[1].y;
        float qA2 = ginA.x * vd[2].x + ginA.y * vd[2].y;
        float qA3 = ginA.x * vd[3].x + ginA.y * vd[3].y;
        float qB0 = ginB.x * vd[0].x + ginB.y * vd[0].y;
        float qB1 = ginB.x * vd[1].x + ginB.y * vd[1].y;
        float qB2 = ginB.x * vd[2].x + ginB.y * vd[2].y;
        float qB3 = ginB.x * vd[3].x + ginB.y * vd[3].y;

        // two interleaved k-transposed butterflies (independent chains)
        const bool bb1 = lane & 1;
        const bool bb2 = lane & 2;
        float aA = bb1 ? qA1 : qA0, aB_ = bb1 ? qA0 : qA1;
        aA += __shfl_xor(aB_, 1, 64);
        float cA = bb1 ? qA3 : qA2, cB_ = bb1 ? qA2 : qA3;
        cA += __shfl_xor(cB_, 1, 64);
        float aX = bb1 ? qB1 : qB0, aY = bb1 ? qB0 : qB1;
        aX += __shfl_xor(aY, 1, 64);
        float cX = bb1 ? qB3 : qB2, cY = bb1 ? qB2 : qB3;
        cX += __shfl_xor(cY, 1, 64);
        float eA = bb2 ? cA : aA, eAB = bb2 ? aA : cA;
        eA += __shfl_xor(eAB, 2, 64);
        float eX = bb2 ? cX : aX, eXY = bb2 ? aX : cX;
        eX += __shfl_xor(eXY, 2, 64);
#pragma unroll
        for (int d = 4; d < 64; d <<= 1) {
            eA += __shfl_xor(eA, d, 64);
            eX += __shfl_xor(eX, d, 64);
        }

        float tA_ = scOwn + eA;
        float lgA = (tA_ >= 0.f) ? tA_ : 0.2f * tA_;
        float tB_ = scOwn + eX;
        float lgB = (tB_ >= 0.f) ? tB_ : 0.2f * tB_;

        // wave-uniform max over both j's and all 4 k's
        float mm = fmaxf(lgA, lgB);
        mm = fmaxf(mm, __shfl_xor(mm, 1, 64));
        mm = fmaxf(mm, __shfl_xor(mm, 2, 64));
        if (mm > m_) {                        // wave-uniform branch
            const float s = __expf(m_ - mm);
            l_ *= s;
#pragma unroll
            for (int k = 0; k < K; ++k) { w0[k] *= s; w1[k] *= s; }
            m_ = mm;
        }
        const float pA = __expf(lgA - m_);
        const float pB = __expf(lgB - m_);
        l_ += pA + pB;

        const float pA0 = readlane_f(pA, 0), pA1 = readlane_f(pA, 1);
        const float pA2 = readlane_f(pA, 2), pA3 = readlane_f(pA, 3);
        const float pB0 = readlane_f(pB, 0), pB1 = readlane_f(pB, 1);
        const float pB2 = readlane_f(pB, 2), pB3 = readlane_f(pB, 3);
        w0[0] += pA0 * ginA.x + pB0 * ginB.x;  w1[0] += pA0 * ginA.y + pB0 * ginB.y;
        w0[1] += pA1 * ginA.x + pB1 * ginB.x;  w1[1] += pA1 * ginA.y + pB1 * ginB.y;
        w0[2] += pA2 * ginA.x + pB2 * ginB.x;  w1[2] += pA2 * ginA.y + pB2 * ginB.y;
        w0[3] += pA3 * ginA.x + pB3 * ginB.x;  w1[3] += pA3 * ginA.y + pB3 * ginB.y;

        jA += 32; jB += 32;
        a2A = a2An; hA = hAn; a2B = a2Bn; hB = hBn;
    }

    // tail: wave 0 handles j = N (goal row)
    if (wid == 0) {
        float tx = a1cc.x + g2v.x + baseI * (u3.x + u4.x);
        float ty = a1cc.y + g2v.y + baseI * (u3.y + u4.y);
        float2 gin = make_float2(hgI.x * sigm(tx), hgI.y * sigm(ty));

        float q0 = gin.x * vd[0].x + gin.y * vd[0].y;
        float q1 = gin.x * vd[1].x + gin.y * vd[1].y;
        float q2 = gin.x * vd[2].x + gin.y * vd[2].y;
        float q3 = gin.x * vd[3].x + gin.y * vd[3].y;

        const bool bb1 = lane & 1;
        const bool bb2 = lane & 2;
        float aA = bb1 ? q1 : q0, aB_ = bb1 ? q0 : q1;
        aA += __shfl_xor(aB_, 1, 64);
        float cA = bb1 ? q3 : q2, cB_ = bb1 ? q2 : q3;
        cA += __shfl_xor(cB_, 1, 64);
        float eA = bb2 ? cA : aA, eAB = bb2 ? aA : cA;
        eA += __shfl_xor(eAB, 2, 64);
#pragma unroll
        for (int d = 4; d < 64; d <<= 1) eA += __shfl_xor(eA, d, 64);

        float tt = scOwn + eA;
        float lg = (tt >= 0.f) ? tt : 0.2f * tt;
        float mm = fmaxf(lg, __shfl_xor(lg, 1, 64));
        mm = fmaxf(mm, __shfl_xor(mm, 2, 64));
        if (mm > m_) {
            const float s = __expf(m_ - mm);
            l_ *= s;
#pragma unroll
            for (int k = 0; k < K; ++k) { w0[k] *= s; w1[k] *= s; }
            m_ = mm;
        }
        const float p = __expf(lg - m_);
        l_ += p;
        const float p0 = readlane_f(p, 0), p1 = readlane_f(p, 1);
        const float p2 = readlane_f(p, 2), p3 = readlane_f(p, 3);
        w0[0] += p0 * gin.x;  w1[0] += p0 * gin.y;
        w0[1] += p1 * gin.x;  w1[1] += p1 * gin.y;
        w0[2] += p2 * gin.x;  w1[2] += p2 * gin.y;
        w0[3] += p3 * gin.x;  w1[3] += p3 * gin.y;
    }

    // dump per-wave partials
#pragma unroll
    for (int k = 0; k < K; ++k)
        *(float2*)&sW[wid][k][f0] = make_float2(w0[k], w1[k]);
    if (lane == 0) sMx[wid] = m_;
    if (lane < K)  sL[wid][lane] = l_;
    __syncthreads();

    // merge 16 wave-partials
    if (tid < H) {
        const int f = tid;
        float Mx = -INFINITY;
#pragma unroll
        for (int w = 0; w < WAVES; ++w) Mx = fmaxf(Mx, sMx[w]);
        float sfac[WAVES];
#pragma unroll
        for (int w = 0; w < WAVES; ++w) sfac[w] = __expf(sMx[w] - Mx);
#pragma unroll
        for (int k = 0; k < K; ++k) {
            float L = 0.f, W = 0.f;
#pragma unroll
            for (int w = 0; w < WAVES; ++w) {
                L += sfac[w] * sL[w][k];
                W += sfac[w] * sW[w][k][f];
            }
            sWfin[k][f] = W / L;
        }
    }
    __syncthreads();

    // epilogue: out[f] = elu( 0.25 * sum_k wfin[k] @ W_gat[k][:,f] + bias[f] )
    {
        const int f = tid & (H - 1);
        const int s = tid >> 7;   // 0..7 -> g-slice of 16
        float acc = 0.0f;
#pragma unroll
        for (int k = 0; k < K; ++k) {
            const int g0 = s * 16;
#pragma unroll
            for (int g = 0; g < 16; ++g)
                acc += sWfin[k][g0 + g] * W_gat[(k * H + g0 + g) * H + f];
        }
        sPart[s][f] = acc;
    }
    __syncthreads();

    if (tid < H) {
        float acc = 0.0f;
#pragma unroll
        for (int s = 0; s < 8; ++s) acc += sPart[s][tid];
        float val = 0.25f * acc + gat_bias[tid];
        out[i * H + tid] = (val > 0.0f) ? val : expm1f(val);
    }
}

// ---------------------------------------------------------------------------
extern "C" void kernel_launch(void* const* d_in, const int* in_sizes, int n_in,
                              void* d_out, int out_size, void* d_ws, size_t ws_size,
                              hipStream_t stream)
{
    const float* ha       = (const float*)d_in[0];
    const float* hg       = (const float*)d_in[1];
    const float* goal     = (const float*)d_in[2];
    const float* action   = (const float*)d_in[3];
    const float* W_emb    = (const float*)d_in[4];
    const float* b_emb    = (const float*)d_in[5];
    const float* W_gate   = (const float*)d_in[6];
    const float* b_gate   = (const float*)d_in[7];
    const float* W_gat    = (const float*)d_in[8];
    const float* a_src    = (const float*)d_in[9];
    const float* a_dst    = (const float*)d_in[10];
    const float* gat_bias = (const float*)d_in[11];

    float* ws  = (float*)d_ws;
    float* A1  = ws;                 // N*H
    float* A2  = A1 + N * H;         // N*H
    float* G2  = A2 + N * H;         // N*H
    float* u3  = G2 + N * H;         // H
    float* u4  = u3 + H;             // H
    float* cc  = u4 + H;             // H
    float* vs  = cc + H;             // K*H
    float* vd  = vs + K * H;         // K*H
    float* outp = (float*)d_out;

    void* args[] = {
        (void*)&ha, (void*)&hg, (void*)&goal, (void*)&action,
        (void*)&W_emb, (void*)&b_emb, (void*)&W_gate, (void*)&b_gate,
        (void*)&W_gat, (void*)&a_src, (void*)&a_dst, (void*)&gat_bias,
        (void*)&A1, (void*)&A2, (void*)&G2,
        (void*)&u3, (void*)&u4, (void*)&cc,
        (void*)&vs, (void*)&vd,
        (void*)&outp
    };

    hipLaunchCooperativeKernel((void*)gat_fused, dim3(N), dim3(BLOCK),
                               args, 0, stream);
}

// Round 4
// 29.536 us; speedup vs baseline: 2.1917x; 2.1917x over previous
//
#include <hip/hip_runtime.h>
#include <math.h>

#define N 256
#define H 128
#define E 64
#define K 4
#define M (N + 1)
#define WAVES 16
#define BLOCK 1024

// ---------------------------------------------------------------------------
// helpers
// ---------------------------------------------------------------------------
__device__ __forceinline__ float sigm(float x) {
    return __fdividef(1.0f, 1.0f + __expf(-x));
}

__device__ __forceinline__ float wave_sum(float v) {
#pragma unroll
    for (int d = 1; d < 64; d <<= 1) v += __shfl_xor(v, d, 64);
    return v;
}

__device__ __forceinline__ float readlane_f(float v, int l) {
    return __uint_as_float(__builtin_amdgcn_readlane(__float_as_uint(v), l));
}

// k-transposed butterfly: lane l ends with  dd[k = l&3] = wave_sum(q_{l&3}).
__device__ __forceinline__ float kbutterfly(float q0, float q1, float q2, float q3,
                                            int lane) {
    const bool b1 = lane & 1;
    const bool b2 = lane & 2;
    float aA = b1 ? q1 : q0, aB = b1 ? q0 : q1;
    aA += __shfl_xor(aB, 1, 64);
    float cA = b1 ? q3 : q2, cB = b1 ? q2 : q3;
    cA += __shfl_xor(cB, 1, 64);
    float eA = b2 ? cA : aA, eB = b2 ? aA : cA;
    eA += __shfl_xor(eB, 2, 64);
#pragma unroll
    for (int d = 4; d < 64; d <<= 1) eA += __shfl_xor(eA, d, 64);
    return eA;
}

// Bit-exact replication of cal_dist's per-pair math (numpy fp32, no FMA
// contraction). Roles: r = row idx, c = col idx, r < c. Returns d[r][c], d[c][r].
__device__ __forceinline__ void pairdist(
    float a1x, float a1y, float a2x, float a2y,
    float g1x, float g1y, float g2x, float g2y,
    float baseR, float baseC, float& d_rc, float& d_cr)
{
    float t  = __fmul_rn(__fsub_rn(a1y, a2y), __fsub_rn(g1x, g2x));
    float dn = -t;  // (a1x-a1x)*(...) == 0 exactly
    float ca = __fsub_rn(__fmul_rn(a1x, a2y), __fmul_rn(a1y, a2x));
    float gt = __fsub_rn(__fmul_rn(g1x, g2y), __fmul_rn(g1x, g2x));  // ref bug kept
    float n1 = __fsub_rn(__fmul_rn(ca, __fsub_rn(g1x, g2x)),
                         __fmul_rn(__fsub_rn(a1x, a2x), gt));
    float n2 = __fsub_rn(__fmul_rn(ca, __fsub_rn(g1y, g2y)),
                         __fmul_rn(__fsub_rn(a1y, a2x), gt));        // ref bug kept
    float safe = (dn == 0.0f) ? 1.0f : dn;
    float p1 = __fdiv_rn(n1, safe);
    float p2 = __fdiv_rn(n2, safe);
    bool cond = (dn != 0.0f) &&
                (__fmul_rn(__fsub_rn(a1x, p1), __fsub_rn(p1, g1x)) > 0.0f);
    float dx1 = __fsub_rn(a1x, p1), dy1 = __fsub_rn(a1y, p2);
    float d1p = __fsqrt_rn(__fadd_rn(__fmul_rn(dx1, dx1), __fmul_rn(dy1, dy1)));
    float dx2 = __fsub_rn(a2x, p1), dy2 = __fsub_rn(a2y, p2);
    float d2p = __fsqrt_rn(__fadd_rn(__fmul_rn(dx2, dx2), __fmul_rn(dy2, dy2)));
    d_rc = cond ? d1p : baseR;
    d_cr = cond ? d2p : baseC;
}

// ---------------------------------------------------------------------------
// Kernel 1: precompute, 256 blocks x 1024 threads (16 waves/CU for TLP)
//   all b   : A1[b]=ha[b]@W1, A2[b]=ha[b]@W2, G2[b]=hg[b]@W2 (8 g-slices)
//   b < 8   : vsrc/vdst slice (coalesced W_gat row reads, wave reduce)
//   b == 8  : u3=W_emb@W3, u4=W_emb@W4, cc=b_emb@(W3+W4)+b_gate
// ---------------------------------------------------------------------------
__global__ __launch_bounds__(BLOCK) void gat_pre(
    const float* __restrict__ ha, const float* __restrict__ hg,
    const float* __restrict__ W_emb, const float* __restrict__ b_emb,
    const float* __restrict__ W_gate, const float* __restrict__ b_gate,
    const float* __restrict__ W_gat, const float* __restrict__ a_src,
    const float* __restrict__ a_dst,
    float* __restrict__ A1, float* __restrict__ A2, float* __restrict__ G2,
    float* __restrict__ u3g, float* __restrict__ u4g, float* __restrict__ ccg,
    float* __restrict__ vsrc, float* __restrict__ vdst)
{
    const int b    = blockIdx.x;
    const int tid  = threadIdx.x;
    const int wid  = tid >> 6;
    const int lane = tid & 63;

    __shared__ float sRed[8][3][H];

    {
        const int f  = tid & (H - 1);
        const int sl = tid >> 7;
        const int g0 = sl * 16;
        float s1 = 0.f, s2 = 0.f, s3 = 0.f;
#pragma unroll
        for (int g = 0; g < 16; ++g) {
            const int gg = g0 + g;
            float w1 = W_gate[gg * H + f];
            float w2 = W_gate[(H + gg) * H + f];
            float av = ha[b * H + gg];
            float gv = hg[b * H + gg];
            s1 += av * w1;
            s2 += av * w2;
            s3 += gv * w2;
        }
        sRed[sl][0][f] = s1;
        sRed[sl][1][f] = s2;
        sRed[sl][2][f] = s3;
    }
    __syncthreads();
    if (tid < H) {
        float r1 = 0.f, r2 = 0.f, r3 = 0.f;
#pragma unroll
        for (int sl = 0; sl < 8; ++sl) {
            r1 += sRed[sl][0][tid];
            r2 += sRed[sl][1][tid];
            r3 += sRed[sl][2][tid];
        }
        A1[b * H + tid] = r1;
        A2[b * H + tid] = r2;
        G2[b * H + tid] = r3;
    }

    if (b < 8) {
        const int k = b >> 1;
        const float2 as = *(const float2*)&a_src[k * H + lane * 2];
        const float2 ad = *(const float2*)&a_dst[k * H + lane * 2];
#pragma unroll
        for (int it = 0; it < 4; ++it) {
            const int pair = b * 64 + wid * 4 + it;
            const int f    = pair & (H - 1);
            const float2 w = *(const float2*)&W_gat[(k * H + f) * H + lane * 2];
            float vs = wave_sum(w.x * as.x + w.y * as.y);
            float vv = wave_sum(w.x * ad.x + w.y * ad.y);
            if (lane == 0) { vsrc[k * H + f] = vs; vdst[k * H + f] = vv; }
        }
    } else if (b == 8) {
        __syncthreads();   // A-row readers done with sRed
        const int f  = tid & (H - 1);
        const int sl = tid >> 7;
        float s3 = 0.f, s4 = 0.f, scc = 0.f;
#pragma unroll
        for (int e0 = 0; e0 < 8; ++e0) {
            const int e = sl * 8 + e0;
            float w3 = W_gate[(2 * H + e) * H + f];
            float w4 = W_gate[(2 * H + E + e) * H + f];
            float we = W_emb[e], be = b_emb[e];
            s3  += we * w3;
            s4  += we * w4;
            scc += be * (w3 + w4);
        }
        sRed[sl][0][f] = s3;
        sRed[sl][1][f] = s4;
        sRed[sl][2][f] = scc;
        __syncthreads();
        if (tid < H) {
            float r3 = 0.f, r4 = 0.f, rc = 0.f;
#pragma unroll
            for (int sl = 0; sl < 8; ++sl) {
                r3 += sRed[sl][0][tid];
                r4 += sRed[sl][1][tid];
                rc += sRed[sl][2][tid];
            }
            u3g[tid] = r3;
            u4g[tid] = r4;
            ccg[tid] = rc + b_gate[tid];
        }
    }
}

// ---------------------------------------------------------------------------
// Kernel 2: main — one block per output row i, 16 waves, unroll-4 j-loop
// ---------------------------------------------------------------------------
__global__ __launch_bounds__(BLOCK) void gat_main(
    const float* __restrict__ ha, const float* __restrict__ hg,
    const float* __restrict__ W_gat, const float* __restrict__ gat_bias,
    const float* __restrict__ A1, const float* __restrict__ A2,
    const float* __restrict__ G2,
    const float* __restrict__ u3a, const float* __restrict__ u4a,
    const float* __restrict__ cca,
    const float* __restrict__ vsrc, const float* __restrict__ vdst,
    const float* __restrict__ goal, const float* __restrict__ action,
    float* __restrict__ out)
{
    const int i    = blockIdx.x;
    const int tid  = threadIdx.x;
    const int wid  = tid >> 6;
    const int lane = tid & 63;
    const int f0   = lane * 2;

    __shared__ float2 sAct[N];
    __shared__ float2 sGoal[N];
    __shared__ float  sBase[N];
    __shared__ float  sDij[M];
    __shared__ float  sDji[M];
    __shared__ float  sW[WAVES][K][H];   // 32 KB
    __shared__ float  sMx[WAVES];
    __shared__ float  sL[WAVES][K];
    __shared__ float  sWfin[K][H];
    __shared__ float  sPart[8][H];

    // ---- issue all per-lane constant loads first (latency hides under pass 0)
    const float2 a1v = *(const float2*)&A1[i * H + f0];
    const float2 haI = *(const float2*)&ha[i * H + f0];
    const float2 hgI = *(const float2*)&hg[i * H + f0];
    const float2 g2v = *(const float2*)&G2[i * H + f0];
    const float2 u3  = *(const float2*)&u3a[f0];
    const float2 u4  = *(const float2*)&u4a[f0];
    const float2 cc  = *(const float2*)&cca[f0];
    float2 vd0 = *(const float2*)&vdst[0 * H + f0];
    float2 vd1 = *(const float2*)&vdst[1 * H + f0];
    float2 vd2 = *(const float2*)&vdst[2 * H + f0];
    float2 vd3 = *(const float2*)&vdst[3 * H + f0];
    float2 vs0 = *(const float2*)&vsrc[0 * H + f0];
    float2 vs1 = *(const float2*)&vsrc[1 * H + f0];
    float2 vs2 = *(const float2*)&vsrc[2 * H + f0];
    float2 vs3 = *(const float2*)&vsrc[3 * H + f0];

    // geometry staging + bit-exact base recompute
    for (int t = tid; t < N; t += BLOCK) {
        float2 a = ((const float2*)action)[t];
        float2 g = ((const float2*)goal)[t];
        sAct[t]  = a;
        sGoal[t] = g;
        float dx = __fsub_rn(a.x, g.x), dy = __fsub_rn(a.y, g.y);
        sBase[t] = __fsqrt_rn(__fadd_rn(__fmul_rn(dx, dx), __fmul_rn(dy, dy)));
    }
    __syncthreads();

    // pass 0: all 257 distance pairs (bit-identical pairdist)
    if (tid < M) {
        const int j = tid;
        float dij = 0.f, dji = 0.f;
        if (j != i && j != N) {
            const float2 aI = sAct[i], gI = sGoal[i];
            const float2 aJ = sAct[j], gJ = sGoal[j];
            if (i < j)
                pairdist(aI.x, aI.y, aJ.x, aJ.y, gI.x, gI.y, gJ.x, gJ.y,
                         sBase[i], sBase[j], dij, dji);
            else
                pairdist(aJ.x, aJ.y, aI.x, aI.y, gJ.x, gJ.y, gI.x, gI.y,
                         sBase[j], sBase[i], dji, dij);
        }
        sDij[j] = dij;
        sDji[j] = dji;
    }

    // sc[k] = ha[i] . v_src[k] via one k-transposed butterfly; lane keeps k=lane&3
    const float scOwn = kbutterfly(haI.x * vs0.x + haI.y * vs0.y,
                                   haI.x * vs1.x + haI.y * vs1.y,
                                   haI.x * vs2.x + haI.y * vs2.y,
                                   haI.x * vs3.x + haI.y * vs3.y, lane);

    const float2 a1cc = make_float2(a1v.x + cc.x, a1v.y + cc.y);
    const float baseI = sBase[i];
    __syncthreads();   // sDij/sDji ready

    // online softmax state (shared wave max m_, own-k l_, per-f w accumulators)
    float m_ = -INFINITY, l_ = 0.f;
    float w00 = 0.f, w01 = 0.f, w02 = 0.f, w03 = 0.f;
    float w10 = 0.f, w11 = 0.f, w12 = 0.f, w13 = 0.f;

    // j-loop: wave owns j = wid + 16s, s=0..15 (j<256), unrolled 4 s-steps/iter
    for (int g = 0; g < 4; ++g) {
        const int j0 = wid + 64 * g;   // + {0,16,32,48}

        float2 a2q[4], hhq[4];
        float dijq[4], djiq[4];
#pragma unroll
        for (int q = 0; q < 4; ++q) {
            const int j = j0 + 16 * q;
            a2q[q]  = *(const float2*)&A2[j * H + f0];
            hhq[q]  = *(const float2*)&ha[j * H + f0];
            dijq[q] = sDij[j];
            djiq[q] = sDji[j];
        }

        float2 gin[4];
#pragma unroll
        for (int q = 0; q < 4; ++q) {
            const int j = j0 + 16 * q;
            float tx = a1cc.x + a2q[q].x + dijq[q] * u3.x + djiq[q] * u4.x;
            float ty = a1cc.y + a2q[q].y + dijq[q] * u3.y + djiq[q] * u4.y;
            float2 gv = make_float2(hhq[q].x * sigm(tx), hhq[q].y * sigm(ty));
            gin[q] = (j == i) ? haI : gv;   // diagonal: ungated ha[i]
        }

        float e[4];
#pragma unroll
        for (int q = 0; q < 4; ++q) {
            e[q] = kbutterfly(gin[q].x * vd0.x + gin[q].y * vd0.y,
                              gin[q].x * vd1.x + gin[q].y * vd1.y,
                              gin[q].x * vd2.x + gin[q].y * vd2.y,
                              gin[q].x * vd3.x + gin[q].y * vd3.y, lane);
        }

        float lg[4];
#pragma unroll
        for (int q = 0; q < 4; ++q) {
            float t = scOwn + e[q];
            lg[q] = (t >= 0.f) ? t : 0.2f * t;   // leaky_relu
        }

        float mm = fmaxf(fmaxf(lg[0], lg[1]), fmaxf(lg[2], lg[3]));
        mm = fmaxf(mm, __shfl_xor(mm, 1, 64));
        mm = fmaxf(mm, __shfl_xor(mm, 2, 64));
        if (mm > m_) {                     // wave-uniform branch
            const float s = __expf(m_ - mm);
            l_ *= s;
            w00 *= s; w01 *= s; w02 *= s; w03 *= s;
            w10 *= s; w11 *= s; w12 *= s; w13 *= s;
            m_ = mm;
        }
        float p[4];
#pragma unroll
        for (int q = 0; q < 4; ++q) p[q] = __expf(lg[q] - m_);
        l_ += (p[0] + p[1]) + (p[2] + p[3]);

#pragma unroll
        for (int q = 0; q < 4; ++q) {
            const float p0 = readlane_f(p[q], 0), p1 = readlane_f(p[q], 1);
            const float p2 = readlane_f(p[q], 2), p3 = readlane_f(p[q], 3);
            w00 += p0 * gin[q].x;  w10 += p0 * gin[q].y;
            w01 += p1 * gin[q].x;  w11 += p1 * gin[q].y;
            w02 += p2 * gin[q].x;  w12 += p2 * gin[q].y;
            w03 += p3 * gin[q].x;  w13 += p3 * gin[q].y;
        }
    }

    // tail: wave 0 handles j = N (goal row)
    if (wid == 0) {
        float tx = a1cc.x + g2v.x + baseI * (u3.x + u4.x);
        float ty = a1cc.y + g2v.y + baseI * (u3.y + u4.y);
        float2 gin = make_float2(hgI.x * sigm(tx), hgI.y * sigm(ty));

        float e = kbutterfly(gin.x * vd0.x + gin.y * vd0.y,
                             gin.x * vd1.x + gin.y * vd1.y,
                             gin.x * vd2.x + gin.y * vd2.y,
                             gin.x * vd3.x + gin.y * vd3.y, lane);
        float t  = scOwn + e;
        float lg = (t >= 0.f) ? t : 0.2f * t;
        float mm = fmaxf(lg, __shfl_xor(lg, 1, 64));
        mm = fmaxf(mm, __shfl_xor(mm, 2, 64));
        if (mm > m_) {
            const float s = __expf(m_ - mm);
            l_ *= s;
            w00 *= s; w01 *= s; w02 *= s; w03 *= s;
            w10 *= s; w11 *= s; w12 *= s; w13 *= s;
            m_ = mm;
        }
        const float p = __expf(lg - m_);
        l_ += p;
        const float p0 = readlane_f(p, 0), p1 = readlane_f(p, 1);
        const float p2 = readlane_f(p, 2), p3 = readlane_f(p, 3);
        w00 += p0 * gin.x;  w10 += p0 * gin.y;
        w01 += p1 * gin.x;  w11 += p1 * gin.y;
        w02 += p2 * gin.x;  w12 += p2 * gin.y;
        w03 += p3 * gin.x;  w13 += p3 * gin.y;
    }

    // dump per-wave partials
    *(float2*)&sW[wid][0][f0] = make_float2(w00, w10);
    *(float2*)&sW[wid][1][f0] = make_float2(w01, w11);
    *(float2*)&sW[wid][2][f0] = make_float2(w02, w12);
    *(float2*)&sW[wid][3][f0] = make_float2(w03, w13);
    if (lane == 0) sMx[wid] = m_;
    if (lane < K)  sL[wid][lane] = l_;
    __syncthreads();

    // merge 16 wave-partials: 512 threads, one (k,f) each
    if (tid < K * H) {
        const int k = tid >> 7;
        const int f = tid & (H - 1);
        float Mx = -INFINITY;
#pragma unroll
        for (int w = 0; w < WAVES; ++w) Mx = fmaxf(Mx, sMx[w]);
        float L = 0.f, W = 0.f;
#pragma unroll
        for (int w = 0; w < WAVES; ++w) {
            const float s = __expf(sMx[w] - Mx);
            L += s * sL[w][k];
            W += s * sW[w][k][f];
        }
        sWfin[k][f] = W / L;
    }
    __syncthreads();

    // epilogue: out[f] = elu( 0.25 * sum_k wfin[k] @ W_gat[k][:,f] + bias[f] )
    {
        const int f = tid & (H - 1);
        const int s = tid >> 7;   // 0..7 -> g-slice of 16
        float acc = 0.0f;
#pragma unroll
        for (int k = 0; k < K; ++k) {
            const int g0 = s * 16;
#pragma unroll
            for (int g = 0; g < 16; ++g)
                acc += sWfin[k][g0 + g] * W_gat[(k * H + g0 + g) * H + f];
        }
        sPart[s][f] = acc;
    }
    __syncthreads();

    if (tid < H) {
        float acc = 0.0f;
#pragma unroll
        for (int s = 0; s < 8; ++s) acc += sPart[s][tid];
        float val = 0.25f * acc + gat_bias[tid];
        out[i * H + tid] = (val > 0.0f) ? val : expm1f(val);
    }
}

// ---------------------------------------------------------------------------
extern "C" void kernel_launch(void* const* d_in, const int* in_sizes, int n_in,
                              void* d_out, int out_size, void* d_ws, size_t ws_size,
                              hipStream_t stream)
{
    const float* ha       = (const float*)d_in[0];
    const float* hg       = (const float*)d_in[1];
    const float* goal     = (const float*)d_in[2];
    const float* action   = (const float*)d_in[3];
    const float* W_emb    = (const float*)d_in[4];
    const float* b_emb    = (const float*)d_in[5];
    const float* W_gate   = (const float*)d_in[6];
    const float* b_gate   = (const float*)d_in[7];
    const float* W_gat    = (const float*)d_in[8];
    const float* a_src    = (const float*)d_in[9];
    const float* a_dst    = (const float*)d_in[10];
    const float* gat_bias = (const float*)d_in[11];

    float* ws  = (float*)d_ws;
    float* A1  = ws;                 // N*H
    float* A2  = A1 + N * H;         // N*H
    float* G2  = A2 + N * H;         // N*H
    float* u3  = G2 + N * H;         // H
    float* u4  = u3 + H;             // H
    float* cc  = u4 + H;             // H
    float* vs  = cc + H;             // K*H
    float* vd  = vs + K * H;         // K*H

    hipLaunchKernelGGL(gat_pre, dim3(N), dim3(BLOCK), 0, stream,
                       ha, hg, W_emb, b_emb, W_gate, b_gate,
                       W_gat, a_src, a_dst,
                       A1, A2, G2, u3, u4, cc, vs, vd);

    hipLaunchKernelGGL(gat_main, dim3(N), dim3(BLOCK), 0, stream,
                       ha, hg, W_gat, gat_bias,
                       A1, A2, G2, u3, u4, cc, vs, vd,
                       goal, action, (float*)d_out);
}

// Round 5
// 28.051 us; speedup vs baseline: 2.3078x; 1.0530x over previous
//
#include <hip/hip_runtime.h>
#include <math.h>

#define N 256
#define H 128
#define E 64
#define K 4
#define M (N + 1)
#define WAVES 16
#define BLOCK 1024

// ---------------------------------------------------------------------------
// helpers
// ---------------------------------------------------------------------------
__device__ __forceinline__ float sigm(float x) {
    return __fdividef(1.0f, 1.0f + __expf(-x));
}

__device__ __forceinline__ float wave_sum(float v) {
#pragma unroll
    for (int d = 1; d < 64; d <<= 1) v += __shfl_xor(v, d, 64);
    return v;
}

// full k-transposed butterfly: lane l ends with wave_sum(q_{l&3})
__device__ __forceinline__ float kbutterfly(float q0, float q1, float q2, float q3,
                                            int lane) {
    const bool b1 = lane & 1;
    const bool b2 = lane & 2;
    float aA = b1 ? q1 : q0, aB = b1 ? q0 : q1;
    aA += __shfl_xor(aB, 1, 64);
    float cA = b1 ? q3 : q2, cB = b1 ? q2 : q3;
    cA += __shfl_xor(cB, 1, 64);
    float eA = b2 ? cA : aA, eB = b2 ? aA : cA;
    eA += __shfl_xor(eB, 2, 64);
#pragma unroll
    for (int d = 4; d < 64; d <<= 1) eA += __shfl_xor(eA, d, 64);
    return eA;
}

// Bit-exact replication of cal_dist's per-pair math (numpy fp32, no FMA
// contraction). Roles: r = row idx, c = col idx, r < c. Returns d[r][c], d[c][r].
__device__ __forceinline__ void pairdist(
    float a1x, float a1y, float a2x, float a2y,
    float g1x, float g1y, float g2x, float g2y,
    float baseR, float baseC, float& d_rc, float& d_cr)
{
    float t  = __fmul_rn(__fsub_rn(a1y, a2y), __fsub_rn(g1x, g2x));
    float dn = -t;  // (a1x-a1x)*(...) == 0 exactly
    float ca = __fsub_rn(__fmul_rn(a1x, a2y), __fmul_rn(a1y, a2x));
    float gt = __fsub_rn(__fmul_rn(g1x, g2y), __fmul_rn(g1x, g2x));  // ref bug kept
    float n1 = __fsub_rn(__fmul_rn(ca, __fsub_rn(g1x, g2x)),
                         __fmul_rn(__fsub_rn(a1x, a2x), gt));
    float n2 = __fsub_rn(__fmul_rn(ca, __fsub_rn(g1y, g2y)),
                         __fmul_rn(__fsub_rn(a1y, a2x), gt));        // ref bug kept
    float safe = (dn == 0.0f) ? 1.0f : dn;
    float p1 = __fdiv_rn(n1, safe);
    float p2 = __fdiv_rn(n2, safe);
    bool cond = (dn != 0.0f) &&
                (__fmul_rn(__fsub_rn(a1x, p1), __fsub_rn(p1, g1x)) > 0.0f);
    float dx1 = __fsub_rn(a1x, p1), dy1 = __fsub_rn(a1y, p2);
    float d1p = __fsqrt_rn(__fadd_rn(__fmul_rn(dx1, dx1), __fmul_rn(dy1, dy1)));
    float dx2 = __fsub_rn(a2x, p1), dy2 = __fsub_rn(a2y, p2);
    float d2p = __fsqrt_rn(__fadd_rn(__fmul_rn(dx2, dx2), __fmul_rn(dy2, dy2)));
    d_rc = cond ? d1p : baseR;
    d_cr = cond ? d2p : baseC;
}

// ---------------------------------------------------------------------------
// Kernel 1: precompute (unchanged from R4), 256 blocks x 1024 threads
// ---------------------------------------------------------------------------
__global__ __launch_bounds__(BLOCK) void gat_pre(
    const float* __restrict__ ha, const float* __restrict__ hg,
    const float* __restrict__ W_emb, const float* __restrict__ b_emb,
    const float* __restrict__ W_gate, const float* __restrict__ b_gate,
    const float* __restrict__ W_gat, const float* __restrict__ a_src,
    const float* __restrict__ a_dst,
    float* __restrict__ A1, float* __restrict__ A2, float* __restrict__ G2,
    float* __restrict__ u3g, float* __restrict__ u4g, float* __restrict__ ccg,
    float* __restrict__ vsrc, float* __restrict__ vdst)
{
    const int b    = blockIdx.x;
    const int tid  = threadIdx.x;
    const int wid  = tid >> 6;
    const int lane = tid & 63;

    __shared__ float sRed[8][3][H];

    {
        const int f  = tid & (H - 1);
        const int sl = tid >> 7;
        const int g0 = sl * 16;
        float s1 = 0.f, s2 = 0.f, s3 = 0.f;
#pragma unroll
        for (int g = 0; g < 16; ++g) {
            const int gg = g0 + g;
            float w1 = W_gate[gg * H + f];
            float w2 = W_gate[(H + gg) * H + f];
            float av = ha[b * H + gg];
            float gv = hg[b * H + gg];
            s1 += av * w1;
            s2 += av * w2;
            s3 += gv * w2;
        }
        sRed[sl][0][f] = s1;
        sRed[sl][1][f] = s2;
        sRed[sl][2][f] = s3;
    }
    __syncthreads();
    if (tid < H) {
        float r1 = 0.f, r2 = 0.f, r3 = 0.f;
#pragma unroll
        for (int sl = 0; sl < 8; ++sl) {
            r1 += sRed[sl][0][tid];
            r2 += sRed[sl][1][tid];
            r3 += sRed[sl][2][tid];
        }
        A1[b * H + tid] = r1;
        A2[b * H + tid] = r2;
        G2[b * H + tid] = r3;
    }

    if (b < 8) {
        const int k = b >> 1;
        const float2 as = *(const float2*)&a_src[k * H + lane * 2];
        const float2 ad = *(const float2*)&a_dst[k * H + lane * 2];
#pragma unroll
        for (int it = 0; it < 4; ++it) {
            const int pair = b * 64 + wid * 4 + it;
            const int f    = pair & (H - 1);
            const float2 w = *(const float2*)&W_gat[(k * H + f) * H + lane * 2];
            float vs = wave_sum(w.x * as.x + w.y * as.y);
            float vv = wave_sum(w.x * ad.x + w.y * ad.y);
            if (lane == 0) { vsrc[k * H + f] = vs; vdst[k * H + f] = vv; }
        }
    } else if (b == 8) {
        __syncthreads();
        const int f  = tid & (H - 1);
        const int sl = tid >> 7;
        float s3 = 0.f, s4 = 0.f, scc = 0.f;
#pragma unroll
        for (int e0 = 0; e0 < 8; ++e0) {
            const int e = sl * 8 + e0;
            float w3 = W_gate[(2 * H + e) * H + f];
            float w4 = W_gate[(2 * H + E + e) * H + f];
            float we = W_emb[e], be = b_emb[e];
            s3  += we * w3;
            s4  += we * w4;
            scc += be * (w3 + w4);
        }
        sRed[sl][0][f] = s3;
        sRed[sl][1][f] = s4;
        sRed[sl][2][f] = scc;
        __syncthreads();
        if (tid < H) {
            float r3 = 0.f, r4 = 0.f, rc = 0.f;
#pragma unroll
            for (int sl = 0; sl < 8; ++sl) {
                r3 += sRed[sl][0][tid];
                r4 += sRed[sl][1][tid];
                rc += sRed[sl][2][tid];
            }
            u3g[tid] = r3;
            u4g[tid] = r4;
            ccg[tid] = rc + b_gate[tid];
        }
    }
}

// ---------------------------------------------------------------------------
// Kernel 2: main — 3-phase (logits / softmax glue / weighted accumulate),
// gin cached in registers between phases A and B. One block per row i.
// ---------------------------------------------------------------------------
__global__ __launch_bounds__(BLOCK) void gat_main(
    const float* __restrict__ ha, const float* __restrict__ hg,
    const float* __restrict__ W_gat, const float* __restrict__ gat_bias,
    const float* __restrict__ A1, const float* __restrict__ A2,
    const float* __restrict__ G2,
    const float* __restrict__ u3a, const float* __restrict__ u4a,
    const float* __restrict__ cca,
    const float* __restrict__ vsrc, const float* __restrict__ vdst,
    const float* __restrict__ goal, const float* __restrict__ action,
    float* __restrict__ out)
{
    const int i    = blockIdx.x;
    const int tid  = threadIdx.x;
    const int wid  = tid >> 6;
    const int lane = tid & 63;
    const int f0   = lane * 2;

    __shared__ float2 sAct[N];
    __shared__ float2 sGoal[N];
    __shared__ float  sBase[N];
    __shared__ float2 sD[M];                        // (d_ij, d_ji) per j
    __shared__ __align__(16) float pbuf[M * K + 4]; // p[j][k], 4.1 KB
    __shared__ float  ssc[K];
    __shared__ float  sMred[WAVES];
    __shared__ float  sLpart[WAVES];
    __shared__ float  sLk[K];
    __shared__ float  sWfin[K][H];
    // time-aliased union: phase A/A2 part[257][33] (33.9KB) -> phase B
    // sW[16][4][128] (32KB) -> epilogue sPart[8][128] (4KB)
    __shared__ __align__(16) char uBuf[34048];
    float* uPart = (float*)uBuf;
    float (*uSW)[K][H]  = (float (*)[K][H])uBuf;
    float (*uEp)[H]     = (float (*)[H])uBuf;

    // ---- issue per-lane constant loads first (latency hides under staging)
    const float2 a1v = *(const float2*)&A1[i * H + f0];
    const float2 haI = *(const float2*)&ha[i * H + f0];
    const float2 hgI = *(const float2*)&hg[i * H + f0];
    const float2 g2v = *(const float2*)&G2[i * H + f0];
    const float2 u3  = *(const float2*)&u3a[f0];
    const float2 u4  = *(const float2*)&u4a[f0];
    const float2 cc  = *(const float2*)&cca[f0];
    const float2 vd0 = *(const float2*)&vdst[0 * H + f0];
    const float2 vd1 = *(const float2*)&vdst[1 * H + f0];
    const float2 vd2 = *(const float2*)&vdst[2 * H + f0];
    const float2 vd3 = *(const float2*)&vdst[3 * H + f0];
    const float2 vs0 = *(const float2*)&vsrc[0 * H + f0];
    const float2 vs1 = *(const float2*)&vsrc[1 * H + f0];
    const float2 vs2 = *(const float2*)&vsrc[2 * H + f0];
    const float2 vs3 = *(const float2*)&vsrc[3 * H + f0];

    // geometry staging + bit-exact base recompute
    for (int t = tid; t < N; t += BLOCK) {
        float2 a = ((const float2*)action)[t];
        float2 g = ((const float2*)goal)[t];
        sAct[t]  = a;
        sGoal[t] = g;
        float dx = __fsub_rn(a.x, g.x), dy = __fsub_rn(a.y, g.y);
        sBase[t] = __fsqrt_rn(__fadd_rn(__fmul_rn(dx, dx), __fmul_rn(dy, dy)));
    }
    __syncthreads();

    // distance pass: one (i,j) pair per thread (bit-identical pairdist)
    if (tid < M) {
        const int j = tid;
        float dij = 0.f, dji = 0.f;
        if (j != i && j != N) {
            const float2 aI = sAct[i], gI = sGoal[i];
            const float2 aJ = sAct[j], gJ = sGoal[j];
            if (i < j)
                pairdist(aI.x, aI.y, aJ.x, aJ.y, gI.x, gI.y, gJ.x, gJ.y,
                         sBase[i], sBase[j], dij, dji);
            else
                pairdist(aJ.x, aJ.y, aI.x, aI.y, gJ.x, gJ.y, gI.x, gI.y,
                         sBase[j], sBase[i], dji, dij);
        }
        sD[j] = make_float2(dij, dji);
    }

    // sc[k] = ha[i] . v_src[k]; lane l holds k = l&3; wave 0 publishes to LDS
    const float scOwn = kbutterfly(haI.x * vs0.x + haI.y * vs0.y,
                                   haI.x * vs1.x + haI.y * vs1.y,
                                   haI.x * vs2.x + haI.y * vs2.y,
                                   haI.x * vs3.x + haI.y * vs3.y, lane);
    if (wid == 0 && lane < K) ssc[lane] = scOwn;

    const float2 a1cc = make_float2(a1v.x + cc.x, a1v.y + cc.y);
    const float baseI = sBase[i];
    __syncthreads();   // sD, ssc ready

    // ================= phase A: gate + dot partials, gin kept in regs ======
    const bool b1 = lane & 1;
    const bool b2 = lane & 2;
    const int  wrIdx   = ((lane >> 3) << 2) + (lane & 3);
    const bool doWrite = !(lane & 4);
    float2 gin[16];

#pragma unroll
    for (int t = 0; t < 16; ++t) {
        const int jj = wid + 16 * t;
        const float2 a2 = *(const float2*)&A2[jj * H + f0];
        const float2 hj = *(const float2*)&ha[jj * H + f0];
        const float2 d  = sD[jj];
        float tx = a1cc.x + a2.x + d.x * u3.x + d.y * u4.x;
        float ty = a1cc.y + a2.y + d.x * u3.y + d.y * u4.y;
        float2 g = make_float2(hj.x * sigm(tx), hj.y * sigm(ty));
        if (jj == i) g = haI;          // diagonal: ungated ha[i]
        gin[t] = g;
        float q0 = g.x * vd0.x + g.y * vd0.y;
        float q1 = g.x * vd1.x + g.y * vd1.y;
        float q2 = g.x * vd2.x + g.y * vd2.y;
        float q3 = g.x * vd3.x + g.y * vd3.y;
        // 3-level k-transposed butterfly -> 8-lane-group partial of dd[k=lane&3]
        float aA = b1 ? q1 : q0, aB = b1 ? q0 : q1;
        aA += __shfl_xor(aB, 1, 64);
        float cA = b1 ? q3 : q2, cB = b1 ? q2 : q3;
        cA += __shfl_xor(cB, 1, 64);
        float eA = b2 ? cA : aA, eB = b2 ? aA : cA;
        eA += __shfl_xor(eB, 2, 64);
        eA += __shfl_xor(eA, 4, 64);
        if (doWrite) uPart[jj * 33 + wrIdx] = eA;   // conflict-free (32 banks)
    }

    // goal row j = N (wave 0 only)
    float2 ginG = make_float2(0.f, 0.f);
    if (wid == 0) {
        float tx = a1cc.x + g2v.x + baseI * (u3.x + u4.x);
        float ty = a1cc.y + g2v.y + baseI * (u3.y + u4.y);
        ginG = make_float2(hgI.x * sigm(tx), hgI.y * sigm(ty));
        float q0 = ginG.x * vd0.x + ginG.y * vd0.y;
        float q1 = ginG.x * vd1.x + ginG.y * vd1.y;
        float q2 = ginG.x * vd2.x + ginG.y * vd2.y;
        float q3 = ginG.x * vd3.x + ginG.y * vd3.y;
        float aA = b1 ? q1 : q0, aB = b1 ? q0 : q1;
        aA += __shfl_xor(aB, 1, 64);
        float cA = b1 ? q3 : q2, cB = b1 ? q2 : q3;
        cA += __shfl_xor(cB, 1, 64);
        float eA = b2 ? cA : aA, eB = b2 ? aA : cA;
        eA += __shfl_xor(eB, 2, 64);
        eA += __shfl_xor(eA, 4, 64);
        if (doWrite) uPart[N * 33 + wrIdx] = eA;
    }
    __syncthreads();   // part complete

    // ================= phase A2: logits -> global softmax -> pbuf, L[k] ====
    const int jq = tid & 255;      // j
    const int kq = tid >> 8;       // k  (wave w covers k = w>>2)
    float dd = 0.f;
#pragma unroll
    for (int g = 0; g < 8; ++g) dd += uPart[jq * 33 + g * 4 + kq];
    float lgq = ssc[kq] + dd;
    lgq = (lgq >= 0.f) ? lgq : 0.2f * lgq;

    float lgT = -INFINITY;
    if (tid < 4) {                 // tail (j=N, k=tid) handled by threads 0..3
        float ddT = 0.f;
#pragma unroll
        for (int g = 0; g < 8; ++g) ddT += uPart[N * 33 + g * 4 + tid];
        lgT = ssc[tid] + ddT;
        lgT = (lgT >= 0.f) ? lgT : 0.2f * lgT;
    }

    float mx = fmaxf(lgq, lgT);
#pragma unroll
    for (int d = 1; d < 64; d <<= 1) mx = fmaxf(mx, __shfl_xor(mx, d, 64));
    if (lane == 0) sMred[wid] = mx;
    __syncthreads();

    float Mg = sMred[0];
#pragma unroll
    for (int w = 1; w < WAVES; ++w) Mg = fmaxf(Mg, sMred[w]);

    const float pq = __expf(lgq - Mg);
    pbuf[jq * 4 + kq] = pq;
    if (tid < 4) pbuf[N * 4 + tid] = __expf(lgT - Mg);

    const float lp = wave_sum(pq);          // wave is k-uniform
    if (lane == 0) sLpart[wid] = lp;
    __syncthreads();                        // pbuf + sLpart ready
    if (tid < 4)
        sLk[tid] = sLpart[tid * 4 + 0] + sLpart[tid * 4 + 1] +
                   sLpart[tid * 4 + 2] + sLpart[tid * 4 + 3] +
                   pbuf[N * 4 + tid];

    // ================= phase B: weighted accumulate with cached gin ========
    float w00 = 0.f, w01 = 0.f, w02 = 0.f, w03 = 0.f;
    float w10 = 0.f, w11 = 0.f, w12 = 0.f, w13 = 0.f;
#pragma unroll
    for (int t = 0; t < 16; ++t) {
        const int jj = wid + 16 * t;
        const float4 p4 = *(const float4*)&pbuf[jj * 4];   // LDS broadcast
        w00 += p4.x * gin[t].x;  w10 += p4.x * gin[t].y;
        w01 += p4.y * gin[t].x;  w11 += p4.y * gin[t].y;
        w02 += p4.z * gin[t].x;  w12 += p4.z * gin[t].y;
        w03 += p4.w * gin[t].x;  w13 += p4.w * gin[t].y;
    }
    if (wid == 0) {   // goal row
        const float4 p4 = *(const float4*)&pbuf[N * 4];
        w00 += p4.x * ginG.x;  w10 += p4.x * ginG.y;
        w01 += p4.y * ginG.x;  w11 += p4.y * ginG.y;
        w02 += p4.z * ginG.x;  w12 += p4.z * ginG.y;
        w03 += p4.w * ginG.x;  w13 += p4.w * ginG.y;
    }

    // dump per-wave partials into the (re-used) union buffer
    *(float2*)&uSW[wid][0][f0] = make_float2(w00, w10);
    *(float2*)&uSW[wid][1][f0] = make_float2(w01, w11);
    *(float2*)&uSW[wid][2][f0] = make_float2(w02, w12);
    *(float2*)&uSW[wid][3][f0] = make_float2(w03, w13);
    __syncthreads();

    // merge 16 wave partials and normalize by L[k]
    if (tid < K * H) {
        const int k = tid >> 7;
        const int f = tid & (H - 1);
        float W = 0.f;
#pragma unroll
        for (int w = 0; w < WAVES; ++w) W += uSW[w][k][f];
        sWfin[k][f] = W / sLk[k];
    }
    __syncthreads();

    // epilogue: out[f] = elu( 0.25 * sum_k wfin[k] @ W_gat[k][:,f] + bias[f] )
    {
        const int f = tid & (H - 1);
        const int s = tid >> 7;   // 0..7 -> g-slice of 16
        float acc = 0.0f;
#pragma unroll
        for (int k = 0; k < K; ++k) {
            const int g0 = s * 16;
#pragma unroll
            for (int g = 0; g < 16; ++g)
                acc += sWfin[k][g0 + g] * W_gat[(k * H + g0 + g) * H + f];
        }
        __syncthreads();          // uSW reads done before overwrite
        uEp[s][f] = acc;
    }
    __syncthreads();

    if (tid < H) {
        float acc = 0.0f;
#pragma unroll
        for (int s = 0; s < 8; ++s) acc += uEp[s][tid];
        float val = 0.25f * acc + gat_bias[tid];
        out[i * H + tid] = (val > 0.0f) ? val : expm1f(val);
    }
}

// ---------------------------------------------------------------------------
extern "C" void kernel_launch(void* const* d_in, const int* in_sizes, int n_in,
                              void* d_out, int out_size, void* d_ws, size_t ws_size,
                              hipStream_t stream)
{
    const float* ha       = (const float*)d_in[0];
    const float* hg       = (const float*)d_in[1];
    const float* goal     = (const float*)d_in[2];
    const float* action   = (const float*)d_in[3];
    const float* W_emb    = (const float*)d_in[4];
    const float* b_emb    = (const float*)d_in[5];
    const float* W_gate   = (const float*)d_in[6];
    const float* b_gate   = (const float*)d_in[7];
    const float* W_gat    = (const float*)d_in[8];
    const float* a_src    = (const float*)d_in[9];
    const float* a_dst    = (const float*)d_in[10];
    const float* gat_bias = (const float*)d_in[11];

    float* ws  = (float*)d_ws;
    float* A1  = ws;                 // N*H
    float* A2  = A1 + N * H;         // N*H
    float* G2  = A2 + N * H;         // N*H
    float* u3  = G2 + N * H;         // H
    float* u4  = u3 + H;             // H
    float* cc  = u4 + H;             // H
    float* vs  = cc + H;             // K*H
    float* vd  = vs + K * H;         // K*H

    hipLaunchKernelGGL(gat_pre, dim3(N), dim3(BLOCK), 0, stream,
                       ha, hg, W_emb, b_emb, W_gate, b_gate,
                       W_gat, a_src, a_dst,
                       A1, A2, G2, u3, u4, cc, vs, vd);

    hipLaunchKernelGGL(gat_main, dim3(N), dim3(BLOCK), 0, stream,
                       ha, hg, W_gat, gat_bias,
                       A1, A2, G2, u3, u4, cc, vs, vd,
                       goal, action, (float*)d_out);
}